// Round 6
// baseline (344.689 us; speedup 1.0000x reference)
//
#include <hip/hip_runtime.h>

#define B_ 8
#define C_ 256
#define N_ 4096

typedef __attribute__((ext_vector_type(8))) __bf16 bf16x8;
typedef __attribute__((ext_vector_type(4))) float f32x4;

__device__ __forceinline__ unsigned short f2bf(float f) {
  union { float f; unsigned u; } v; v.f = f;
  unsigned r = v.u + 0x7fffu + ((v.u >> 16) & 1u);
  return (unsigned short)(r >> 16);
}

__device__ __forceinline__ uint4 pack8(const float* s) {
  uint4 o;
  o.x = (unsigned)f2bf(s[0]) | ((unsigned)f2bf(s[1]) << 16);
  o.y = (unsigned)f2bf(s[2]) | ((unsigned)f2bf(s[3]) << 16);
  o.z = (unsigned)f2bf(s[4]) | ((unsigned)f2bf(s[5]) << 16);
  o.w = (unsigned)f2bf(s[6]) | ((unsigned)f2bf(s[7]) << 16);
  return o;
}

// v_cvt_pk_bf16_f32: a->low16, b->high16 (RNE, same as f2bf)
__device__ __forceinline__ unsigned cvtpk(float a, float b) {
  unsigned r;
  asm("v_cvt_pk_bf16_f32 %0, %1, %2" : "=v"(r) : "v"(a), "v"(b));
  return r;
}

// async global->LDS DMA, 16 B per lane; LDS dest = wave-uniform base + lane*16
__device__ __forceinline__ void dma16(const void* g, void* l) {
  __builtin_amdgcn_global_load_lds(
      (const __attribute__((address_space(1))) unsigned int*)(uintptr_t)g,
      (__attribute__((address_space(3))) unsigned int*)(uintptr_t)l, 16, 0, 0);
}

// ---------------------------------------------------------------------------
// Kernel 0: prep — xT[b][n][c] = bf16(x[b][c][n]) via u32-packed LDS transpose
// plus W{q,k,v} f32->bf16 once, plus zeroing the 512 pair-handshake flags.
// Grid (64, 4, 8), 256 thr.
// ---------------------------------------------------------------------------
__global__ __launch_bounds__(256) void prep(
    const float* __restrict__ x,
    const float* __restrict__ Wq, const float* __restrict__ Wk,
    const float* __restrict__ Wv,
    unsigned short* __restrict__ xT, unsigned short* __restrict__ Wbf,
    unsigned int* __restrict__ flags)
{
  __shared__ unsigned int xTl[64][33];   // [n][cpair], stride 33 => 2-way banks
  const int t   = threadIdx.x;
  const int n0  = blockIdx.x * 64;
  const int ct0 = blockIdx.y * 64;
  const int b   = blockIdx.z;

  if (blockIdx.z == 0) {
    const int bid = blockIdx.x + 64 * blockIdx.y;
    if (bid < 96) {
      const int el0 = (bid * 256 + t) * 8;
      const int mat = el0 >> 16;
      const int off = el0 & 65535;
      const float* src = (mat == 0) ? Wq : (mat == 1) ? Wk : Wv;
      float tmp[8];
      float4 f0 = ((const float4*)(src + off))[0];
      float4 f1 = ((const float4*)(src + off))[1];
      tmp[0]=f0.x; tmp[1]=f0.y; tmp[2]=f0.z; tmp[3]=f0.w;
      tmp[4]=f1.x; tmp[5]=f1.y; tmp[6]=f1.z; tmp[7]=f1.w;
      *(uint4*)(Wbf + el0) = pack8(tmp);
    }
    if (bid == 96) {            // zero arrive[256] + ready[256] every launch
      flags[t] = 0u;
      flags[256 + t] = 0u;
    }
  }

  {
    const int cp = t >> 3;
    const int nq = t & 7;
    const float* s0 = x + ((size_t)(b * C_ + ct0 + 2*cp) * N_ + n0 + nq * 8);
    const float* s1 = s0 + N_;
    float4 a0 = ((const float4*)s0)[0], a1 = ((const float4*)s0)[1];
    float4 b0 = ((const float4*)s1)[0], b1 = ((const float4*)s1)[1];
    float lo[8] = {a0.x,a0.y,a0.z,a0.w,a1.x,a1.y,a1.z,a1.w};
    float hi[8] = {b0.x,b0.y,b0.z,b0.w,b1.x,b1.y,b1.z,b1.w};
    #pragma unroll
    for (int k = 0; k < 8; ++k)
      xTl[nq*8 + k][cp] = (unsigned)f2bf(lo[k]) | ((unsigned)f2bf(hi[k]) << 16);
  }
  __syncthreads();

  {
    const int n = t >> 2, cq = t & 3;
    unsigned int vals[8];
    #pragma unroll
    for (int g = 0; g < 8; ++g) vals[g] = xTl[n][cq*8 + g];
    uint4* dst = (uint4*)(xT + ((size_t)(b * N_ + n0 + n)) * C_ + ct0 + cq*16);
    dst[0] = make_uint4(vals[0], vals[1], vals[2], vals[3]);
    dst[1] = make_uint4(vals[4], vals[5], vals[6], vals[7]);
  }
}

// ---------------------------------------------------------------------------
// Kernel 1: QKV GEMM — V (mat==2) stored with j-interleave permutation within
// each 32-n block: storage pos p <-> j = 16*((p>>2)&1) + 4*(p>>3) + (p&3),
// so attn's PV consumes lane-local P fragments with zero cross-lane ops.
// Grid (32 ntiles, 8 b, 3 mats), 256 thr.
// ---------------------------------------------------------------------------
__global__ __launch_bounds__(256, 2) void qkv_gemm(
    const unsigned short* __restrict__ xT, const unsigned short* __restrict__ Wbf,
    const float* __restrict__ bq, const float* __restrict__ bk,
    const float* __restrict__ bv,
    unsigned short* __restrict__ qT, unsigned short* __restrict__ kT,
    unsigned short* __restrict__ vW)
{
  __shared__ char smraw[49152];

  const int t    = threadIdx.x;
  const int lane = t & 63;
  const int w    = t >> 6;
  const int m16  = lane & 15;
  const int q    = (lane >> 4) & 3;
  const int nt0  = blockIdx.x * 128;
  const int b    = blockIdx.y;
  const int mat  = blockIdx.z;
  const size_t bN = (size_t)b * N_;

  const unsigned short* Wm = Wbf + mat * 65536;
  const float* bm = (mat == 0) ? bq : (mat == 1) ? bk : bv;
  unsigned short* outp = (mat == 0) ? qT : (mat == 1) ? kT : vW;

  auto stage = [&](int buf, int cs) {
    #pragma unroll
    for (int p = 0; p < 4; ++p) {
      const int row = 64 * w + 16 * p + (lane >> 2);
      const int g   = (lane & 3) ^ (row & 3);
      dma16(Wm + row * 256 + cs * 32 + g * 8,
            smraw + buf * 16384 + (64 * w + 16 * p) * 64);
    }
    #pragma unroll
    for (int p = 0; p < 2; ++p) {
      const int row = 32 * w + 16 * p + (lane >> 2);
      const int g   = (lane & 3) ^ (row & 3);
      dma16(xT + (bN + nt0 + row) * 256 + cs * 32 + g * 8,
            smraw + 32768 + buf * 8192 + (32 * w + 16 * p) * 64);
    }
  };

  stage(0, 0);

  float br[4][4];
  #pragma unroll
  for (int ob = 0; ob < 4; ++ob)
    #pragma unroll
    for (int r = 0; r < 4; ++r) br[ob][r] = bm[64*w + ob*16 + q*4 + r];

  f32x4 acc[4][8] = {};

  for (int cs = 0; cs < 8; ++cs) {
    asm volatile("s_waitcnt vmcnt(0)" ::: "memory");
    __syncthreads();
    if (cs + 1 < 8) stage((cs + 1) & 1, cs + 1);
    const int buf = cs & 1;
    const unsigned short* Wt = (const unsigned short*)(smraw + buf * 16384);
    const unsigned short* Xt = (const unsigned short*)(smraw + 32768 + buf * 8192);

    bf16x8 af[4], bf_[8];
    #pragma unroll
    for (int ob = 0; ob < 4; ++ob) {
      const int o = 64*w + ob*16 + m16;
      af[ob] = *(const bf16x8*)&Wt[o * 32 + ((q ^ (o & 3)) * 8)];
    }
    #pragma unroll
    for (int nb = 0; nb < 8; ++nb) {
      const int n = nb*16 + m16;
      bf_[nb] = *(const bf16x8*)&Xt[n * 32 + ((q ^ (n & 3)) * 8)];
    }
    #pragma unroll
    for (int ob = 0; ob < 4; ++ob)
      #pragma unroll
      for (int nb = 0; nb < 8; ++nb)
        acc[ob][nb] = __builtin_amdgcn_mfma_f32_16x16x32_bf16(af[ob], bf_[nb], acc[ob][nb], 0,0,0);
  }

  float* Dst = (float*)smraw;
  for (int nc = 0; nc < 4; ++nc) {
    __syncthreads();
    #pragma unroll
    for (int ob = 0; ob < 4; ++ob)
      #pragma unroll
      for (int h = 0; h < 2; ++h) {
        const int nb = nc*2 + h;
        #pragma unroll
        for (int r = 0; r < 4; ++r)
          Dst[(64*w + ob*16 + q*4 + r) * 36 + h*16 + m16] = acc[ob][nb][r] + br[ob][r];
      }
    __syncthreads();

    if (mat < 2) {      // (N, C) layout
      const int n_loc = t & 31, oc = t >> 5;
      float vals[32];
      #pragma unroll
      for (int k = 0; k < 32; ++k) vals[k] = Dst[(oc*32 + k) * 36 + n_loc];
      uint4* dst = (uint4*)(outp + (bN + nt0 + nc*32 + n_loc) * C_ + oc*32);
      #pragma unroll
      for (int g = 0; g < 4; ++g) dst[g] = pack8(vals + g*8);
    } else {            // (C, N) layout, j-interleave permuted per 32-block
      float vals[32], pv[32];
      #pragma unroll
      for (int k = 0; k < 32; ++k) vals[k] = Dst[t * 36 + k];
      #pragma unroll
      for (int p = 0; p < 32; ++p)
        pv[p] = vals[16*((p>>2)&1) + 4*(p>>3) + (p&3)];
      uint4* dst = (uint4*)(outp + ((size_t)(b * C_ + t)) * N_ + nt0 + nc*32);
      #pragma unroll
      for (int g = 0; g < 4; ++g) dst[g] = pack8(pv + g*8);
    }
  }
}

// ---------------------------------------------------------------------------
// Kernel 2: attn11 = attn9 (champion: 32 i/wave, j-split, 2 blocks/CU) with
//  (a) FUSED COMBINE: per (b,itile) the two jh-blocks handshake via atomics;
//      first finisher writes partial O+l, second combines in-register and
//      writes `out` directly (no combine kernel, -64 MB epilogue traffic).
//      Deadlock-free: the spinner's partner already passed its atomicAdd, so
//      it is running and will set `ready` regardless of scheduling order.
//      out = gm*(Omine+Otheirs)/((lm+lt)*64)+x; f32 add is commutative =>
//      result is identical whichever block finishes first.
//  (b) XCD swizzle: 1-D grid, b = lin&7 -> with round-robin XCD dispatch each
//      XCD works on one b; its kT/vW/qT slices (2 MB each) stay L2-resident.
//  (c) cvt_pk bf16 packing (8 cvt_pk replace 16 f2bf ~ 48 VALU ops /iter).
// Grid (512), 256 thr.
// ---------------------------------------------------------------------------
__global__ __launch_bounds__(256, 2) void attn11(
    const unsigned short* __restrict__ qT, const unsigned short* __restrict__ kT,
    const unsigned short* __restrict__ vW, const float* __restrict__ x,
    const float* __restrict__ gamma,
    float* __restrict__ Opart, float* __restrict__ lpart,
    unsigned int* __restrict__ arrive, unsigned int* __restrict__ ready,
    float* __restrict__ out)
{
  __shared__ unsigned short Kbuf[2][32 * 256];   // 16 KB each, swz ^(j&7)
  __shared__ unsigned short Vbuf[3][256 * 32];   // 16 KB each, swz ^((c>>1)&3)
  __shared__ unsigned int role;

  const int t    = threadIdx.x;
  const int lane = t & 63;
  const int w    = t >> 6;
  const int lin  = blockIdx.x;
  const int b    = lin & 7;               // XCD-aligned batch
  const int itile = (lin >> 3) & 31;
  const int jh   = lin >> 8;
  const int i0   = itile * 128;
  const int jbase = jh * 2048;
  const int m16  = lane & 15;
  const int q    = (lane >> 4) & 3;
  const int q8   = q * 8;
  const size_t bN = (size_t)b * N_;
  const size_t bC = (size_t)b * C_;
  const int f    = b * 32 + itile;        // pair id

  auto stageK = [&](int buf, int j0) {
    #pragma unroll
    for (int p = 0; p < 4; ++p) {          // K: 32 rows x 32 granules
      const int row = 8*w + 2*p + (lane >> 5);
      const int g   = (lane & 31) ^ (row & 7);
      dma16(kT + (bN + j0 + row) * C_ + g * 8, &Kbuf[buf][(8*w + 2*p) * 256]);
    }
  };
  auto stageV = [&](int buf, int j0) {
    #pragma unroll
    for (int p = 0; p < 4; ++p) {          // V: 256 rows x 4 granules
      const int row = 64*w + 16*p + (lane >> 2);
      const int g   = (lane & 3) ^ ((row >> 1) & 3);
      dma16(vW + (bC + row) * N_ + j0 + g * 8, &Vbuf[buf][(64*w + 16*p) * 32]);
    }
  };

  stageK(0, jbase); stageV(0, jbase);

  // Q fragments resident for BOTH i-subtiles: iA = i0+w*32+m16, iB = iA+16
  bf16x8 qfA[8], qfB[8];
  {
    const unsigned short* qa = qT + ((bN + i0 + w*32 + m16) * C_ + q8);
    const unsigned short* qb = qa + 16 * C_;
    #pragma unroll
    for (int ks = 0; ks < 8; ++ks) {
      qfA[ks] = *(const bf16x8*)(qa + ks*32);
      qfB[ks] = *(const bf16x8*)(qb + ks*32);
    }
  }

  float lA = 0.0f, lB = 0.0f;
  f32x4 OA[16] = {}, OB[16] = {};   // O^T: col=i (lane&15), row=c (q*4+reg)
  uint4 pkA, pkB;
  int vb_prev = 0;

  // ---- peeled iter 0: S + softmax only (no PV yet) ----
  {
    asm volatile("s_waitcnt vmcnt(0)" ::: "memory");
    __syncthreads();
    stageK(1, jbase + 32); stageV(1, jbase + 32);
    const unsigned short* Kt = Kbuf[0];

    f32x4 sA[2] = {}, sB[2] = {};
    __builtin_amdgcn_s_setprio(1);
    #pragma unroll
    for (int ks = 0; ks < 8; ++ks)
      #pragma unroll
      for (int jb = 0; jb < 2; ++jb) {
        const int j = jb*16 + m16;
        bf16x8 a = *(const bf16x8*)&Kt[j * 256 + (((4*ks + q) ^ (j & 7)) * 8)];
        sA[jb] = __builtin_amdgcn_mfma_f32_16x16x32_bf16(a, qfA[ks], sA[jb], 0,0,0);
        sB[jb] = __builtin_amdgcn_mfma_f32_16x16x32_bf16(a, qfB[ks], sB[jb], 0,0,0);
      }
    __builtin_amdgcn_s_setprio(0);

    float psA[2][4], psB[2][4];
    #pragma unroll
    for (int jb = 0; jb < 2; ++jb)
      #pragma unroll
      for (int r = 0; r < 4; ++r) {
        const float pa = __expf(sA[jb][r] - 64.0f);
        const float pb = __expf(sB[jb][r] - 64.0f);
        psA[jb][r] = pa; lA += pa;
        psB[jb][r] = pb; lB += pb;
      }
    pkA.x = cvtpk(psA[0][0], psA[0][1]); pkA.y = cvtpk(psA[0][2], psA[0][3]);
    pkA.z = cvtpk(psA[1][0], psA[1][1]); pkA.w = cvtpk(psA[1][2], psA[1][3]);
    pkB.x = cvtpk(psB[0][0], psB[0][1]); pkB.y = cvtpk(psB[0][2], psB[0][3]);
    pkB.z = cvtpk(psB[1][0], psB[1][1]); pkB.w = cvtpk(psB[1][2], psB[1][3]);
  }

  // ---- main loop: iter jt does S(jt) || PV(jt-1), then softmax(jt) ----
  for (int jt = 1; jt < 64; ++jt) {
    asm volatile("s_waitcnt vmcnt(0)" ::: "memory");
    __syncthreads();
    const int vb_cur = (vb_prev == 2) ? 0 : vb_prev + 1;       // jt % 3
    const int vb_nxt = (vb_cur == 2) ? 0 : vb_cur + 1;         // (jt+1) % 3
    if (jt + 1 < 64) { stageK((jt + 1) & 1, jbase + (jt + 1) * 32);
                       stageV(vb_nxt, jbase + (jt + 1) * 32); }

    const unsigned short* Kt = Kbuf[jt & 1];
    const unsigned short* Vp = Vbuf[vb_prev];
    union { uint4 u; bf16x8 v; } pva; pva.u = pkA;
    union { uint4 u; bf16x8 v; } pvb; pvb.u = pkB;

    f32x4 sA[2] = {}, sB[2] = {};
    __builtin_amdgcn_s_setprio(1);
    // per u: one K-frag read -> 2 S-MFMAs; one V-frag read -> 2 PV-MFMAs
    #pragma unroll
    for (int u = 0; u < 16; ++u) {
      {
        const int ks = u >> 1, jb = u & 1;
        const int j = jb*16 + m16;
        bf16x8 a = *(const bf16x8*)&Kt[j * 256 + (((4*ks + q) ^ (j & 7)) * 8)];
        sA[jb] = __builtin_amdgcn_mfma_f32_16x16x32_bf16(a, qfA[ks], sA[jb], 0,0,0);
        sB[jb] = __builtin_amdgcn_mfma_f32_16x16x32_bf16(a, qfB[ks], sB[jb], 0,0,0);
      }
      {
        const int c = u*16 + m16;
        bf16x8 vf = *(const bf16x8*)&Vp[c * 32 + ((q ^ ((c >> 1) & 3)) * 8)];
        OA[u] = __builtin_amdgcn_mfma_f32_16x16x32_bf16(vf, pva.v, OA[u], 0,0,0);
        OB[u] = __builtin_amdgcn_mfma_f32_16x16x32_bf16(vf, pvb.v, OB[u], 0,0,0);
      }
    }
    __builtin_amdgcn_s_setprio(0);

    // softmax(jt): p = exp(S - 64)
    float psA[2][4], psB[2][4];
    #pragma unroll
    for (int jb = 0; jb < 2; ++jb)
      #pragma unroll
      for (int r = 0; r < 4; ++r) {
        const float pa = __expf(sA[jb][r] - 64.0f);
        const float pb = __expf(sB[jb][r] - 64.0f);
        psA[jb][r] = pa; lA += pa;
        psB[jb][r] = pb; lB += pb;
      }
    pkA.x = cvtpk(psA[0][0], psA[0][1]); pkA.y = cvtpk(psA[0][2], psA[0][3]);
    pkA.z = cvtpk(psA[1][0], psA[1][1]); pkA.w = cvtpk(psA[1][2], psA[1][3]);
    pkB.x = cvtpk(psB[0][0], psB[0][1]); pkB.y = cvtpk(psB[0][2], psB[0][3]);
    pkB.z = cvtpk(psB[1][0], psB[1][1]); pkB.w = cvtpk(psB[1][2], psB[1][3]);
    vb_prev = vb_cur;
  }

  // ---- tail: PV(63) ----
  {
    const unsigned short* Vp = Vbuf[vb_prev];
    union { uint4 u; bf16x8 v; } pva; pva.u = pkA;
    union { uint4 u; bf16x8 v; } pvb; pvb.u = pkB;
    __builtin_amdgcn_s_setprio(1);
    #pragma unroll
    for (int cb = 0; cb < 16; ++cb) {
      const int c = cb*16 + m16;
      bf16x8 vf = *(const bf16x8*)&Vp[c * 32 + ((q ^ ((c >> 1) & 3)) * 8)];
      OA[cb] = __builtin_amdgcn_mfma_f32_16x16x32_bf16(vf, pva.v, OA[cb], 0,0,0);
      OB[cb] = __builtin_amdgcn_mfma_f32_16x16x32_bf16(vf, pvb.v, OB[cb], 0,0,0);
    }
    __builtin_amdgcn_s_setprio(0);
  }

  // --- reduce l across q-groups ---
  float lAs = lA;
  lAs += __shfl_xor(lAs, 16);
  lAs += __shfl_xor(lAs, 32);
  float lBs = lB;
  lBs += __shfl_xor(lBs, 16);
  lBs += __shfl_xor(lBs, 32);

  const int icolA = i0 + w*32 + m16;

  // --- pair handshake: exactly one block per f gets role==0 (first) ---
  __syncthreads();
  if (t == 0) role = atomicAdd(&arrive[f], 1u);
  __syncthreads();

  if (role == 0) {
    // FIRST finisher: write partial O (unscaled f32) + partial l, then ready.
    if (lane < 16) {
      lpart[bN + icolA]      = lAs;
      lpart[bN + icolA + 16] = lBs;
    }
    #pragma unroll
    for (int cb = 0; cb < 16; ++cb) {
      #pragma unroll
      for (int r = 0; r < 4; ++r) {
        const int c = cb*16 + q*4 + r;
        const size_t idx = (bC + c) * N_ + icolA;
        Opart[idx]      = OA[cb][r];
        Opart[idx + 16] = OB[cb][r];
      }
    }
    // __syncthreads drains each wave's vmcnt => stores device-visible (L1 is
    // write-through on CDNA) before thread 0 publishes.
    __syncthreads();
    if (t == 0)
      __hip_atomic_store(&ready[f], 1u, __ATOMIC_RELEASE, __HIP_MEMORY_SCOPE_AGENT);
  } else {
    // SECOND finisher: partner is past its atomicAdd => running => bounded spin.
    while (__hip_atomic_load(&ready[f], __ATOMIC_ACQUIRE,
                             __HIP_MEMORY_SCOPE_AGENT) == 0u)
      __builtin_amdgcn_s_sleep(1);

    const float gm  = gamma[0];
    const float lA2 = lpart[bN + icolA];
    const float lB2 = lpart[bN + icolA + 16];
    const float fsA = gm / ((lAs + lA2) * 64.0f);
    const float fsB = gm / ((lBs + lB2) * 64.0f);
    #pragma unroll
    for (int cb = 0; cb < 16; ++cb) {
      #pragma unroll
      for (int r = 0; r < 4; ++r) {
        const int c = cb*16 + q*4 + r;
        const size_t idx = (bC + c) * N_ + icolA;
        out[idx]      = (OA[cb][r] + Opart[idx])      * fsA + x[idx];
        out[idx + 16] = (OB[cb][r] + Opart[idx + 16]) * fsB + x[idx + 16];
      }
    }
  }
}

extern "C" void kernel_launch(void* const* d_in, const int* in_sizes, int n_in,
                              void* d_out, int out_size, void* d_ws, size_t ws_size,
                              hipStream_t stream) {
  const float* x     = (const float*)d_in[0];
  const float* Wq    = (const float*)d_in[1];
  const float* bq    = (const float*)d_in[2];
  const float* Wk    = (const float*)d_in[3];
  const float* bk    = (const float*)d_in[4];
  const float* Wv    = (const float*)d_in[5];
  const float* bv    = (const float*)d_in[6];
  const float* gamma = (const float*)d_in[7];
  float* out = (float*)d_out;

  unsigned short* xT  = (unsigned short*)d_ws;            // 16 MB
  unsigned short* Wbf = xT + (size_t)B_ * N_ * C_;        // 384 KB
  unsigned short* qT  = Wbf + 3 * 65536;                  // 16 MB
  unsigned short* kT  = qT + (size_t)B_ * N_ * C_;        // 16 MB
  unsigned short* vW  = kT + (size_t)B_ * N_ * C_;        // 16 MB
  float* Opart = (float*)(vW + (size_t)B_ * N_ * C_);     // 32 MB partial O
  float* lpart = Opart + (size_t)B_ * C_ * N_;            // 128 KB partial l
  unsigned int* arrive = (unsigned int*)(lpart + (size_t)B_ * N_);  // 1 KB
  unsigned int* ready  = arrive + 256;                               // 1 KB

  prep<<<dim3(64, 4, 8), dim3(256), 0, stream>>>(x, Wq, Wk, Wv, xT, Wbf, arrive);
  qkv_gemm<<<dim3(32, 8, 3), dim3(256), 0, stream>>>(xT, Wbf, bq, bk, bv, qT, kT, vW);
  attn11<<<dim3(512), dim3(256), 0, stream>>>(qT, kT, vW, x, gamma,
                                              Opart, lpart, arrive, ready, out);
}

// Round 7
// 302.145 us; speedup vs baseline: 1.1408x; 1.1408x over previous
//
#include <hip/hip_runtime.h>

#define B_ 8
#define C_ 256
#define N_ 4096

typedef __attribute__((ext_vector_type(8))) __bf16 bf16x8;
typedef __attribute__((ext_vector_type(4))) float f32x4;

__device__ __forceinline__ unsigned short f2bf(float f) {
  union { float f; unsigned u; } v; v.f = f;
  unsigned r = v.u + 0x7fffu + ((v.u >> 16) & 1u);
  return (unsigned short)(r >> 16);
}

__device__ __forceinline__ uint4 pack8(const float* s) {
  uint4 o;
  o.x = (unsigned)f2bf(s[0]) | ((unsigned)f2bf(s[1]) << 16);
  o.y = (unsigned)f2bf(s[2]) | ((unsigned)f2bf(s[3]) << 16);
  o.z = (unsigned)f2bf(s[4]) | ((unsigned)f2bf(s[5]) << 16);
  o.w = (unsigned)f2bf(s[6]) | ((unsigned)f2bf(s[7]) << 16);
  return o;
}

// v_cvt_pk_bf16_f32: a->low16, b->high16 (RNE, same as f2bf)
__device__ __forceinline__ unsigned cvtpk(float a, float b) {
  unsigned r;
  asm("v_cvt_pk_bf16_f32 %0, %1, %2" : "=v"(r) : "v"(a), "v"(b));
  return r;
}

// async global->LDS DMA, 16 B per lane; LDS dest = wave-uniform base + lane*16
__device__ __forceinline__ void dma16(const void* g, void* l) {
  __builtin_amdgcn_global_load_lds(
      (const __attribute__((address_space(1))) unsigned int*)(uintptr_t)g,
      (__attribute__((address_space(3))) unsigned int*)(uintptr_t)l, 16, 0, 0);
}

// ---------------------------------------------------------------------------
// Kernel 0: prep — xT[b][n][c] = bf16(x[b][c][n]) via u32-packed LDS transpose
// plus W{q,k,v} f32->bf16 once, plus zeroing the 512 pair-handshake flags.
// Grid (64, 4, 8), 256 thr.
// ---------------------------------------------------------------------------
__global__ __launch_bounds__(256) void prep(
    const float* __restrict__ x,
    const float* __restrict__ Wq, const float* __restrict__ Wk,
    const float* __restrict__ Wv,
    unsigned short* __restrict__ xT, unsigned short* __restrict__ Wbf,
    unsigned int* __restrict__ flags)
{
  __shared__ unsigned int xTl[64][33];   // [n][cpair], stride 33 => 2-way banks
  const int t   = threadIdx.x;
  const int n0  = blockIdx.x * 64;
  const int ct0 = blockIdx.y * 64;
  const int b   = blockIdx.z;

  if (blockIdx.z == 0) {
    const int bid = blockIdx.x + 64 * blockIdx.y;
    if (bid < 96) {
      const int el0 = (bid * 256 + t) * 8;
      const int mat = el0 >> 16;
      const int off = el0 & 65535;
      const float* src = (mat == 0) ? Wq : (mat == 1) ? Wk : Wv;
      float tmp[8];
      float4 f0 = ((const float4*)(src + off))[0];
      float4 f1 = ((const float4*)(src + off))[1];
      tmp[0]=f0.x; tmp[1]=f0.y; tmp[2]=f0.z; tmp[3]=f0.w;
      tmp[4]=f1.x; tmp[5]=f1.y; tmp[6]=f1.z; tmp[7]=f1.w;
      *(uint4*)(Wbf + el0) = pack8(tmp);
    }
    if (bid == 96) {            // zero arrive[256] + ready[256] every launch
      flags[t] = 0u;
      flags[256 + t] = 0u;
    }
  }

  {
    const int cp = t >> 3;
    const int nq = t & 7;
    const float* s0 = x + ((size_t)(b * C_ + ct0 + 2*cp) * N_ + n0 + nq * 8);
    const float* s1 = s0 + N_;
    float4 a0 = ((const float4*)s0)[0], a1 = ((const float4*)s0)[1];
    float4 b0 = ((const float4*)s1)[0], b1 = ((const float4*)s1)[1];
    float lo[8] = {a0.x,a0.y,a0.z,a0.w,a1.x,a1.y,a1.z,a1.w};
    float hi[8] = {b0.x,b0.y,b0.z,b0.w,b1.x,b1.y,b1.z,b1.w};
    #pragma unroll
    for (int k = 0; k < 8; ++k)
      xTl[nq*8 + k][cp] = (unsigned)f2bf(lo[k]) | ((unsigned)f2bf(hi[k]) << 16);
  }
  __syncthreads();

  {
    const int n = t >> 2, cq = t & 3;
    unsigned int vals[8];
    #pragma unroll
    for (int g = 0; g < 8; ++g) vals[g] = xTl[n][cq*8 + g];
    uint4* dst = (uint4*)(xT + ((size_t)(b * N_ + n0 + n)) * C_ + ct0 + cq*16);
    dst[0] = make_uint4(vals[0], vals[1], vals[2], vals[3]);
    dst[1] = make_uint4(vals[4], vals[5], vals[6], vals[7]);
  }
}

// ---------------------------------------------------------------------------
// Kernel 1: QKV GEMM — V (mat==2) stored with j-interleave permutation within
// each 32-n block: storage pos p <-> j = 16*((p>>2)&1) + 4*(p>>3) + (p&3),
// so attn's PV consumes lane-local P fragments with zero cross-lane ops.
// Grid (32 ntiles, 8 b, 3 mats), 256 thr.
// ---------------------------------------------------------------------------
__global__ __launch_bounds__(256, 2) void qkv_gemm(
    const unsigned short* __restrict__ xT, const unsigned short* __restrict__ Wbf,
    const float* __restrict__ bq, const float* __restrict__ bk,
    const float* __restrict__ bv,
    unsigned short* __restrict__ qT, unsigned short* __restrict__ kT,
    unsigned short* __restrict__ vW)
{
  __shared__ char smraw[49152];

  const int t    = threadIdx.x;
  const int lane = t & 63;
  const int w    = t >> 6;
  const int m16  = lane & 15;
  const int q    = (lane >> 4) & 3;
  const int nt0  = blockIdx.x * 128;
  const int b    = blockIdx.y;
  const int mat  = blockIdx.z;
  const size_t bN = (size_t)b * N_;

  const unsigned short* Wm = Wbf + mat * 65536;
  const float* bm = (mat == 0) ? bq : (mat == 1) ? bk : bv;
  unsigned short* outp = (mat == 0) ? qT : (mat == 1) ? kT : vW;

  auto stage = [&](int buf, int cs) {
    #pragma unroll
    for (int p = 0; p < 4; ++p) {
      const int row = 64 * w + 16 * p + (lane >> 2);
      const int g   = (lane & 3) ^ (row & 3);
      dma16(Wm + row * 256 + cs * 32 + g * 8,
            smraw + buf * 16384 + (64 * w + 16 * p) * 64);
    }
    #pragma unroll
    for (int p = 0; p < 2; ++p) {
      const int row = 32 * w + 16 * p + (lane >> 2);
      const int g   = (lane & 3) ^ (row & 3);
      dma16(xT + (bN + nt0 + row) * 256 + cs * 32 + g * 8,
            smraw + 32768 + buf * 8192 + (32 * w + 16 * p) * 64);
    }
  };

  stage(0, 0);

  float br[4][4];
  #pragma unroll
  for (int ob = 0; ob < 4; ++ob)
    #pragma unroll
    for (int r = 0; r < 4; ++r) br[ob][r] = bm[64*w + ob*16 + q*4 + r];

  f32x4 acc[4][8] = {};

  for (int cs = 0; cs < 8; ++cs) {
    asm volatile("s_waitcnt vmcnt(0)" ::: "memory");
    __syncthreads();
    if (cs + 1 < 8) stage((cs + 1) & 1, cs + 1);
    const int buf = cs & 1;
    const unsigned short* Wt = (const unsigned short*)(smraw + buf * 16384);
    const unsigned short* Xt = (const unsigned short*)(smraw + 32768 + buf * 8192);

    bf16x8 af[4], bf_[8];
    #pragma unroll
    for (int ob = 0; ob < 4; ++ob) {
      const int o = 64*w + ob*16 + m16;
      af[ob] = *(const bf16x8*)&Wt[o * 32 + ((q ^ (o & 3)) * 8)];
    }
    #pragma unroll
    for (int nb = 0; nb < 8; ++nb) {
      const int n = nb*16 + m16;
      bf_[nb] = *(const bf16x8*)&Xt[n * 32 + ((q ^ (n & 3)) * 8)];
    }
    #pragma unroll
    for (int ob = 0; ob < 4; ++ob)
      #pragma unroll
      for (int nb = 0; nb < 8; ++nb)
        acc[ob][nb] = __builtin_amdgcn_mfma_f32_16x16x32_bf16(af[ob], bf_[nb], acc[ob][nb], 0,0,0);
  }

  float* Dst = (float*)smraw;
  for (int nc = 0; nc < 4; ++nc) {
    __syncthreads();
    #pragma unroll
    for (int ob = 0; ob < 4; ++ob)
      #pragma unroll
      for (int h = 0; h < 2; ++h) {
        const int nb = nc*2 + h;
        #pragma unroll
        for (int r = 0; r < 4; ++r)
          Dst[(64*w + ob*16 + q*4 + r) * 36 + h*16 + m16] = acc[ob][nb][r] + br[ob][r];
      }
    __syncthreads();

    if (mat < 2) {      // (N, C) layout
      const int n_loc = t & 31, oc = t >> 5;
      float vals[32];
      #pragma unroll
      for (int k = 0; k < 32; ++k) vals[k] = Dst[(oc*32 + k) * 36 + n_loc];
      uint4* dst = (uint4*)(outp + (bN + nt0 + nc*32 + n_loc) * C_ + oc*32);
      #pragma unroll
      for (int g = 0; g < 4; ++g) dst[g] = pack8(vals + g*8);
    } else {            // (C, N) layout, j-interleave permuted per 32-block
      float vals[32], pv[32];
      #pragma unroll
      for (int k = 0; k < 32; ++k) vals[k] = Dst[t * 36 + k];
      #pragma unroll
      for (int p = 0; p < 32; ++p)
        pv[p] = vals[16*((p>>2)&1) + 4*(p>>3) + (p&3)];
      uint4* dst = (uint4*)(outp + ((size_t)(b * C_ + t)) * N_ + nt0 + nc*32);
      #pragma unroll
      for (int g = 0; g < 4; ++g) dst[g] = pack8(pv + g*8);
    }
  }
}

// ---------------------------------------------------------------------------
// Kernel 2: attn12 = attn11 with the LDS overflow fixed: the role broadcast
// reuses Kbuf[0] (dead after the last S-iteration) instead of a dedicated
// __shared__ variable, keeping LDS at exactly 81920 B => 2 blocks/CU (the
// proven-necessary occupancy). Fused combine handshake otherwise identical
// to the passing attn11: first jh-finisher per (b,itile) writes partial O+l;
// second combines in-register and writes out directly. Deadlock-free (the
// spinner's partner already passed its atomicAdd => it is running).
// Grid (512), 256 thr.
// ---------------------------------------------------------------------------
__global__ __launch_bounds__(256, 2) void attn12(
    const unsigned short* __restrict__ qT, const unsigned short* __restrict__ kT,
    const unsigned short* __restrict__ vW, const float* __restrict__ x,
    const float* __restrict__ gamma,
    float* __restrict__ Opart, float* __restrict__ lpart,
    unsigned int* __restrict__ arrive, unsigned int* __restrict__ ready,
    float* __restrict__ out)
{
  __shared__ unsigned short Kbuf[2][32 * 256];   // 16 KB each, swz ^(j&7)
  __shared__ unsigned short Vbuf[3][256 * 32];   // 16 KB each, swz ^((c>>1)&3)
  // total LDS = 81920 exactly; role is broadcast through Kbuf[0] post-loop.

  const int t    = threadIdx.x;
  const int lane = t & 63;
  const int w    = t >> 6;
  const int lin  = blockIdx.x;
  const int b    = lin & 7;               // XCD-aligned batch
  const int itile = (lin >> 3) & 31;
  const int jh   = lin >> 8;
  const int i0   = itile * 128;
  const int jbase = jh * 2048;
  const int m16  = lane & 15;
  const int q    = (lane >> 4) & 3;
  const int q8   = q * 8;
  const size_t bN = (size_t)b * N_;
  const size_t bC = (size_t)b * C_;
  const int f    = b * 32 + itile;        // pair id

  auto stageK = [&](int buf, int j0) {
    #pragma unroll
    for (int p = 0; p < 4; ++p) {          // K: 32 rows x 32 granules
      const int row = 8*w + 2*p + (lane >> 5);
      const int g   = (lane & 31) ^ (row & 7);
      dma16(kT + (bN + j0 + row) * C_ + g * 8, &Kbuf[buf][(8*w + 2*p) * 256]);
    }
  };
  auto stageV = [&](int buf, int j0) {
    #pragma unroll
    for (int p = 0; p < 4; ++p) {          // V: 256 rows x 4 granules
      const int row = 64*w + 16*p + (lane >> 2);
      const int g   = (lane & 3) ^ ((row >> 1) & 3);
      dma16(vW + (bC + row) * N_ + j0 + g * 8, &Vbuf[buf][(64*w + 16*p) * 32]);
    }
  };

  stageK(0, jbase); stageV(0, jbase);

  // Q fragments resident for BOTH i-subtiles: iA = i0+w*32+m16, iB = iA+16
  bf16x8 qfA[8], qfB[8];
  {
    const unsigned short* qa = qT + ((bN + i0 + w*32 + m16) * C_ + q8);
    const unsigned short* qb = qa + 16 * C_;
    #pragma unroll
    for (int ks = 0; ks < 8; ++ks) {
      qfA[ks] = *(const bf16x8*)(qa + ks*32);
      qfB[ks] = *(const bf16x8*)(qb + ks*32);
    }
  }

  float lA = 0.0f, lB = 0.0f;
  f32x4 OA[16] = {}, OB[16] = {};   // O^T: col=i (lane&15), row=c (q*4+reg)
  uint4 pkA, pkB;
  int vb_prev = 0;

  // ---- peeled iter 0: S + softmax only (no PV yet) ----
  {
    asm volatile("s_waitcnt vmcnt(0)" ::: "memory");
    __syncthreads();
    stageK(1, jbase + 32); stageV(1, jbase + 32);
    const unsigned short* Kt = Kbuf[0];

    f32x4 sA[2] = {}, sB[2] = {};
    __builtin_amdgcn_s_setprio(1);
    #pragma unroll
    for (int ks = 0; ks < 8; ++ks)
      #pragma unroll
      for (int jb = 0; jb < 2; ++jb) {
        const int j = jb*16 + m16;
        bf16x8 a = *(const bf16x8*)&Kt[j * 256 + (((4*ks + q) ^ (j & 7)) * 8)];
        sA[jb] = __builtin_amdgcn_mfma_f32_16x16x32_bf16(a, qfA[ks], sA[jb], 0,0,0);
        sB[jb] = __builtin_amdgcn_mfma_f32_16x16x32_bf16(a, qfB[ks], sB[jb], 0,0,0);
      }
    __builtin_amdgcn_s_setprio(0);

    float psA[2][4], psB[2][4];
    #pragma unroll
    for (int jb = 0; jb < 2; ++jb)
      #pragma unroll
      for (int r = 0; r < 4; ++r) {
        const float pa = __expf(sA[jb][r] - 64.0f);
        const float pb = __expf(sB[jb][r] - 64.0f);
        psA[jb][r] = pa; lA += pa;
        psB[jb][r] = pb; lB += pb;
      }
    pkA.x = cvtpk(psA[0][0], psA[0][1]); pkA.y = cvtpk(psA[0][2], psA[0][3]);
    pkA.z = cvtpk(psA[1][0], psA[1][1]); pkA.w = cvtpk(psA[1][2], psA[1][3]);
    pkB.x = cvtpk(psB[0][0], psB[0][1]); pkB.y = cvtpk(psB[0][2], psB[0][3]);
    pkB.z = cvtpk(psB[1][0], psB[1][1]); pkB.w = cvtpk(psB[1][2], psB[1][3]);
  }

  // ---- main loop: iter jt does S(jt) || PV(jt-1), then softmax(jt) ----
  for (int jt = 1; jt < 64; ++jt) {
    asm volatile("s_waitcnt vmcnt(0)" ::: "memory");
    __syncthreads();
    const int vb_cur = (vb_prev == 2) ? 0 : vb_prev + 1;       // jt % 3
    const int vb_nxt = (vb_cur == 2) ? 0 : vb_cur + 1;         // (jt+1) % 3
    if (jt + 1 < 64) { stageK((jt + 1) & 1, jbase + (jt + 1) * 32);
                       stageV(vb_nxt, jbase + (jt + 1) * 32); }

    const unsigned short* Kt = Kbuf[jt & 1];
    const unsigned short* Vp = Vbuf[vb_prev];
    union { uint4 u; bf16x8 v; } pva; pva.u = pkA;
    union { uint4 u; bf16x8 v; } pvb; pvb.u = pkB;

    f32x4 sA[2] = {}, sB[2] = {};
    __builtin_amdgcn_s_setprio(1);
    // per u: one K-frag read -> 2 S-MFMAs; one V-frag read -> 2 PV-MFMAs
    #pragma unroll
    for (int u = 0; u < 16; ++u) {
      {
        const int ks = u >> 1, jb = u & 1;
        const int j = jb*16 + m16;
        bf16x8 a = *(const bf16x8*)&Kt[j * 256 + (((4*ks + q) ^ (j & 7)) * 8)];
        sA[jb] = __builtin_amdgcn_mfma_f32_16x16x32_bf16(a, qfA[ks], sA[jb], 0,0,0);
        sB[jb] = __builtin_amdgcn_mfma_f32_16x16x32_bf16(a, qfB[ks], sB[jb], 0,0,0);
      }
      {
        const int c = u*16 + m16;
        bf16x8 vf = *(const bf16x8*)&Vp[c * 32 + ((q ^ ((c >> 1) & 3)) * 8)];
        OA[u] = __builtin_amdgcn_mfma_f32_16x16x32_bf16(vf, pva.v, OA[u], 0,0,0);
        OB[u] = __builtin_amdgcn_mfma_f32_16x16x32_bf16(vf, pvb.v, OB[u], 0,0,0);
      }
    }
    __builtin_amdgcn_s_setprio(0);

    // softmax(jt): p = exp(S - 64)
    float psA[2][4], psB[2][4];
    #pragma unroll
    for (int jb = 0; jb < 2; ++jb)
      #pragma unroll
      for (int r = 0; r < 4; ++r) {
        const float pa = __expf(sA[jb][r] - 64.0f);
        const float pb = __expf(sB[jb][r] - 64.0f);
        psA[jb][r] = pa; lA += pa;
        psB[jb][r] = pb; lB += pb;
      }
    pkA.x = cvtpk(psA[0][0], psA[0][1]); pkA.y = cvtpk(psA[0][2], psA[0][3]);
    pkA.z = cvtpk(psA[1][0], psA[1][1]); pkA.w = cvtpk(psA[1][2], psA[1][3]);
    pkB.x = cvtpk(psB[0][0], psB[0][1]); pkB.y = cvtpk(psB[0][2], psB[0][3]);
    pkB.z = cvtpk(psB[1][0], psB[1][1]); pkB.w = cvtpk(psB[1][2], psB[1][3]);
    vb_prev = vb_cur;
  }

  // ---- tail: PV(63) (reads Vbuf only; Kbuf is dead from here) ----
  {
    const unsigned short* Vp = Vbuf[vb_prev];
    union { uint4 u; bf16x8 v; } pva; pva.u = pkA;
    union { uint4 u; bf16x8 v; } pvb; pvb.u = pkB;
    __builtin_amdgcn_s_setprio(1);
    #pragma unroll
    for (int cb = 0; cb < 16; ++cb) {
      const int c = cb*16 + m16;
      bf16x8 vf = *(const bf16x8*)&Vp[c * 32 + ((q ^ ((c >> 1) & 3)) * 8)];
      OA[cb] = __builtin_amdgcn_mfma_f32_16x16x32_bf16(vf, pva.v, OA[cb], 0,0,0);
      OB[cb] = __builtin_amdgcn_mfma_f32_16x16x32_bf16(vf, pvb.v, OB[cb], 0,0,0);
    }
    __builtin_amdgcn_s_setprio(0);
  }

  // --- reduce l across q-groups ---
  float lAs = lA;
  lAs += __shfl_xor(lAs, 16);
  lAs += __shfl_xor(lAs, 32);
  float lBs = lB;
  lBs += __shfl_xor(lBs, 16);
  lBs += __shfl_xor(lBs, 32);

  const int icolA = i0 + w*32 + m16;

  // --- pair handshake: role broadcast through Kbuf[0] (LDS reuse, no extra
  //     allocation). Barrier first: all waves are past their Kbuf reads. ---
  unsigned int* rolep = (unsigned int*)&Kbuf[0][0];
  __syncthreads();
  if (t == 0) *rolep = atomicAdd(&arrive[f], 1u);
  __syncthreads();
  const unsigned int role = *rolep;

  if (role == 0) {
    // FIRST finisher: write partial O (unscaled f32) + partial l, then ready.
    if (lane < 16) {
      lpart[bN + icolA]      = lAs;
      lpart[bN + icolA + 16] = lBs;
    }
    #pragma unroll
    for (int cb = 0; cb < 16; ++cb) {
      #pragma unroll
      for (int r = 0; r < 4; ++r) {
        const int c = cb*16 + q*4 + r;
        const size_t idx = (bC + c) * N_ + icolA;
        Opart[idx]      = OA[cb][r];
        Opart[idx + 16] = OB[cb][r];
      }
    }
    // __syncthreads drains each wave's outstanding stores before publish.
    __syncthreads();
    if (t == 0)
      __hip_atomic_store(&ready[f], 1u, __ATOMIC_RELEASE, __HIP_MEMORY_SCOPE_AGENT);
  } else {
    // SECOND finisher: partner is past its atomicAdd => running => bounded spin.
    while (__hip_atomic_load(&ready[f], __ATOMIC_ACQUIRE,
                             __HIP_MEMORY_SCOPE_AGENT) == 0u)
      __builtin_amdgcn_s_sleep(1);

    const float gm  = gamma[0];
    const float lA2 = lpart[bN + icolA];
    const float lB2 = lpart[bN + icolA + 16];
    const float fsA = gm / ((lAs + lA2) * 64.0f);
    const float fsB = gm / ((lBs + lB2) * 64.0f);
    #pragma unroll
    for (int cb = 0; cb < 16; ++cb) {
      #pragma unroll
      for (int r = 0; r < 4; ++r) {
        const int c = cb*16 + q*4 + r;
        const size_t idx = (bC + c) * N_ + icolA;
        out[idx]      = (OA[cb][r] + Opart[idx])      * fsA + x[idx];
        out[idx + 16] = (OB[cb][r] + Opart[idx + 16]) * fsB + x[idx + 16];
      }
    }
  }
}

extern "C" void kernel_launch(void* const* d_in, const int* in_sizes, int n_in,
                              void* d_out, int out_size, void* d_ws, size_t ws_size,
                              hipStream_t stream) {
  const float* x     = (const float*)d_in[0];
  const float* Wq    = (const float*)d_in[1];
  const float* bq    = (const float*)d_in[2];
  const float* Wk    = (const float*)d_in[3];
  const float* bk    = (const float*)d_in[4];
  const float* Wv    = (const float*)d_in[5];
  const float* bv    = (const float*)d_in[6];
  const float* gamma = (const float*)d_in[7];
  float* out = (float*)d_out;

  unsigned short* xT  = (unsigned short*)d_ws;            // 16 MB
  unsigned short* Wbf = xT + (size_t)B_ * N_ * C_;        // 384 KB
  unsigned short* qT  = Wbf + 3 * 65536;                  // 16 MB
  unsigned short* kT  = qT + (size_t)B_ * N_ * C_;        // 16 MB
  unsigned short* vW  = kT + (size_t)B_ * N_ * C_;        // 16 MB
  float* Opart = (float*)(vW + (size_t)B_ * N_ * C_);     // 32 MB partial O
  float* lpart = Opart + (size_t)B_ * C_ * N_;            // 128 KB partial l
  unsigned int* arrive = (unsigned int*)(lpart + (size_t)B_ * N_);  // 1 KB
  unsigned int* ready  = arrive + 256;                               // 1 KB

  prep<<<dim3(64, 4, 8), dim3(256), 0, stream>>>(x, Wq, Wk, Wv, xT, Wbf, arrive);
  qkv_gemm<<<dim3(32, 8, 3), dim3(256), 0, stream>>>(xT, Wbf, bq, bk, bv, qT, kT, vW);
  attn12<<<dim3(512), dim3(256), 0, stream>>>(qT, kT, vW, x, gamma,
                                              Opart, lpart, arrive, ready, out);
}

// Round 8
// 294.172 us; speedup vs baseline: 1.1717x; 1.0271x over previous
//
#include <hip/hip_runtime.h>

#define B_ 8
#define C_ 256
#define N_ 4096

typedef __attribute__((ext_vector_type(8))) __bf16 bf16x8;
typedef __attribute__((ext_vector_type(4))) float f32x4;

__device__ __forceinline__ unsigned short f2bf(float f) {
  union { float f; unsigned u; } v; v.f = f;
  unsigned r = v.u + 0x7fffu + ((v.u >> 16) & 1u);
  return (unsigned short)(r >> 16);
}

__device__ __forceinline__ uint4 pack8(const float* s) {
  uint4 o;
  o.x = (unsigned)f2bf(s[0]) | ((unsigned)f2bf(s[1]) << 16);
  o.y = (unsigned)f2bf(s[2]) | ((unsigned)f2bf(s[3]) << 16);
  o.z = (unsigned)f2bf(s[4]) | ((unsigned)f2bf(s[5]) << 16);
  o.w = (unsigned)f2bf(s[6]) | ((unsigned)f2bf(s[7]) << 16);
  return o;
}

// async global->LDS DMA, 16 B per lane; LDS dest = wave-uniform base + lane*16
__device__ __forceinline__ void dma16(const void* g, void* l) {
  __builtin_amdgcn_global_load_lds(
      (const __attribute__((address_space(1))) unsigned int*)(uintptr_t)g,
      (__attribute__((address_space(3))) unsigned int*)(uintptr_t)l, 16, 0, 0);
}

// ---------------------------------------------------------------------------
// Kernel 0: prep — xT[b][n][c] = bf16(x[b][c][n]) via u32-packed LDS transpose
// plus W{q,k,v} f32->bf16 once. Grid (64, 4, 8), 256 thr.  (round-0 verbatim)
// ---------------------------------------------------------------------------
__global__ __launch_bounds__(256) void prep(
    const float* __restrict__ x,
    const float* __restrict__ Wq, const float* __restrict__ Wk,
    const float* __restrict__ Wv,
    unsigned short* __restrict__ xT, unsigned short* __restrict__ Wbf)
{
  __shared__ unsigned int xTl[64][33];   // [n][cpair], stride 33 => 2-way banks
  const int t   = threadIdx.x;
  const int n0  = blockIdx.x * 64;
  const int ct0 = blockIdx.y * 64;
  const int b   = blockIdx.z;

  if (blockIdx.z == 0) {
    const int bid = blockIdx.x + 64 * blockIdx.y;
    if (bid < 96) {
      const int el0 = (bid * 256 + t) * 8;
      const int mat = el0 >> 16;
      const int off = el0 & 65535;
      const float* src = (mat == 0) ? Wq : (mat == 1) ? Wk : Wv;
      float tmp[8];
      float4 f0 = ((const float4*)(src + off))[0];
      float4 f1 = ((const float4*)(src + off))[1];
      tmp[0]=f0.x; tmp[1]=f0.y; tmp[2]=f0.z; tmp[3]=f0.w;
      tmp[4]=f1.x; tmp[5]=f1.y; tmp[6]=f1.z; tmp[7]=f1.w;
      *(uint4*)(Wbf + el0) = pack8(tmp);
    }
  }

  {
    const int cp = t >> 3;
    const int nq = t & 7;
    const float* s0 = x + ((size_t)(b * C_ + ct0 + 2*cp) * N_ + n0 + nq * 8);
    const float* s1 = s0 + N_;
    float4 a0 = ((const float4*)s0)[0], a1 = ((const float4*)s0)[1];
    float4 b0 = ((const float4*)s1)[0], b1 = ((const float4*)s1)[1];
    float lo[8] = {a0.x,a0.y,a0.z,a0.w,a1.x,a1.y,a1.z,a1.w};
    float hi[8] = {b0.x,b0.y,b0.z,b0.w,b1.x,b1.y,b1.z,b1.w};
    #pragma unroll
    for (int k = 0; k < 8; ++k)
      xTl[nq*8 + k][cp] = (unsigned)f2bf(lo[k]) | ((unsigned)f2bf(hi[k]) << 16);
  }
  __syncthreads();

  {
    const int n = t >> 2, cq = t & 3;
    unsigned int vals[8];
    #pragma unroll
    for (int g = 0; g < 8; ++g) vals[g] = xTl[n][cq*8 + g];
    uint4* dst = (uint4*)(xT + ((size_t)(b * N_ + n0 + n)) * C_ + ct0 + cq*16);
    dst[0] = make_uint4(vals[0], vals[1], vals[2], vals[3]);
    dst[1] = make_uint4(vals[4], vals[5], vals[6], vals[7]);
  }
}

// ---------------------------------------------------------------------------
// Kernel 1: QKV GEMM v2 — RETILED FOR OCCUPANCY. n-tile 128 -> 64: per-wave
// acc 32 -> 16 fragments (64 VGPR), LDS 48 -> 40 KB dbuf, launch_bounds
// (256,3) => 3-4 blocks/CU (vs 2). The 8-step barrier chain's staging latency
// now hides across 3-4 independent blocks per CU. Staging / fragment /
// epilogue patterns unchanged from the proven kernel. V (mat==2) keeps the
// j-interleave permutation per 32-n block that attn5's PV consumes.
// Grid (64 ntiles, 8 b, 3 mats), 256 thr.
// ---------------------------------------------------------------------------
__global__ __launch_bounds__(256, 3) void qkv_gemm(
    const unsigned short* __restrict__ xT, const unsigned short* __restrict__ Wbf,
    const float* __restrict__ bq, const float* __restrict__ bk,
    const float* __restrict__ bv,
    unsigned short* __restrict__ qT, unsigned short* __restrict__ kT,
    unsigned short* __restrict__ vW)
{
  __shared__ char smraw[40960];   // dbuf: buf*20480 = W 16384 + X 4096

  const int t    = threadIdx.x;
  const int lane = t & 63;
  const int w    = t >> 6;
  const int m16  = lane & 15;
  const int q    = (lane >> 4) & 3;
  const int nt0  = blockIdx.x * 64;
  const int b    = blockIdx.y;
  const int mat  = blockIdx.z;
  const size_t bN = (size_t)b * N_;

  const unsigned short* Wm = Wbf + mat * 65536;
  const float* bm = (mat == 0) ? bq : (mat == 1) ? bk : bv;
  unsigned short* outp = (mat == 0) ? qT : (mat == 1) ? kT : vW;

  auto stage = [&](int buf, int cs) {
    #pragma unroll
    for (int p = 0; p < 4; ++p) {        // W: 256 rows x 32 c
      const int row = 64 * w + 16 * p + (lane >> 2);
      const int g   = (lane & 3) ^ (row & 3);
      dma16(Wm + row * 256 + cs * 32 + g * 8,
            smraw + buf * 20480 + (64 * w + 16 * p) * 64);
    }
    {                                     // X: 64 rows x 32 c
      const int row = 16 * w + (lane >> 2);
      const int g   = (lane & 3) ^ (row & 3);
      dma16(xT + (bN + nt0 + row) * 256 + cs * 32 + g * 8,
            smraw + buf * 20480 + 16384 + (16 * w) * 64);
    }
  };

  stage(0, 0);

  float br[4][4];
  #pragma unroll
  for (int ob = 0; ob < 4; ++ob)
    #pragma unroll
    for (int r = 0; r < 4; ++r) br[ob][r] = bm[64*w + ob*16 + q*4 + r];

  f32x4 acc[4][4] = {};

  for (int cs = 0; cs < 8; ++cs) {
    asm volatile("s_waitcnt vmcnt(0)" ::: "memory");
    __syncthreads();
    if (cs + 1 < 8) stage((cs + 1) & 1, cs + 1);
    const int buf = cs & 1;
    const unsigned short* Wt = (const unsigned short*)(smraw + buf * 20480);
    const unsigned short* Xt = (const unsigned short*)(smraw + buf * 20480 + 16384);

    bf16x8 af[4], bf_[4];
    #pragma unroll
    for (int ob = 0; ob < 4; ++ob) {
      const int o = 64*w + ob*16 + m16;
      af[ob] = *(const bf16x8*)&Wt[o * 32 + ((q ^ (o & 3)) * 8)];
    }
    #pragma unroll
    for (int nb = 0; nb < 4; ++nb) {
      const int n = nb*16 + m16;
      bf_[nb] = *(const bf16x8*)&Xt[n * 32 + ((q ^ (n & 3)) * 8)];
    }
    #pragma unroll
    for (int ob = 0; ob < 4; ++ob)
      #pragma unroll
      for (int nb = 0; nb < 4; ++nb)
        acc[ob][nb] = __builtin_amdgcn_mfma_f32_16x16x32_bf16(af[ob], bf_[nb], acc[ob][nb], 0,0,0);
  }

  float* Dst = (float*)smraw;            // 256*36*4 = 36864 <= 40960
  for (int nc = 0; nc < 2; ++nc) {
    __syncthreads();
    #pragma unroll
    for (int ob = 0; ob < 4; ++ob)
      #pragma unroll
      for (int h = 0; h < 2; ++h) {
        const int nb = nc*2 + h;
        #pragma unroll
        for (int r = 0; r < 4; ++r)
          Dst[(64*w + ob*16 + q*4 + r) * 36 + h*16 + m16] = acc[ob][nb][r] + br[ob][r];
      }
    __syncthreads();

    if (mat < 2) {      // (N, C) layout
      const int n_loc = t & 31, oc = t >> 5;
      float vals[32];
      #pragma unroll
      for (int k = 0; k < 32; ++k) vals[k] = Dst[(oc*32 + k) * 36 + n_loc];
      uint4* dst = (uint4*)(outp + (bN + nt0 + nc*32 + n_loc) * C_ + oc*32);
      #pragma unroll
      for (int g = 0; g < 4; ++g) dst[g] = pack8(vals + g*8);
    } else {            // (C, N) layout, j-interleave permuted per 32-block
      float vals[32], pv[32];
      #pragma unroll
      for (int k = 0; k < 32; ++k) vals[k] = Dst[t * 36 + k];
      #pragma unroll
      for (int p = 0; p < 32; ++p)
        pv[p] = vals[16*((p>>2)&1) + 4*(p>>3) + (p&3)];
      uint4* dst = (uint4*)(outp + ((size_t)(b * C_ + t)) * N_ + nt0 + nc*32);
      #pragma unroll
      for (int g = 0; g < 4; ++g) dst[g] = pack8(pv + g*8);
    }
  }
}

// ---------------------------------------------------------------------------
// Kernel 2: flash attention, fixed-max softmax (M0=64) — round-0 attn5
// verbatim (harness-proven 184.6 us champion). 256 thr (4 waves), wave owns
// 16 i; j-tile 32 double-buffered; 64 KB LDS; V j-interleave-permuted so each
// lane's PV A-fragment is ONE conflict-free ds_read_b128.
// Grid (8 b, 64 itiles).
// ---------------------------------------------------------------------------
__global__ __launch_bounds__(256, 2) void attn5(
    const unsigned short* __restrict__ qT, const unsigned short* __restrict__ kT,
    const unsigned short* __restrict__ vW, const float* __restrict__ x,
    const float* __restrict__ gamma, float* __restrict__ out)
{
  __shared__ unsigned short Kbuf[2][32 * 256];   // 16 KB each, swz ^(j&7)
  __shared__ unsigned short Vbuf[2][256 * 32];   // 16 KB each, swz ^((c>>1)&3)

  const int t    = threadIdx.x;
  const int lane = t & 63;
  const int w    = t >> 6;
  const int b    = blockIdx.x;
  const int i0   = blockIdx.y * 64;
  const int m16  = lane & 15;
  const int q    = (lane >> 4) & 3;
  const int q8   = q * 8;
  const size_t bN = (size_t)b * N_;
  const size_t bC = (size_t)b * C_;

  auto stage = [&](int buf, int j0) {
    #pragma unroll
    for (int p = 0; p < 4; ++p) {          // K: 32 rows x 32 granules
      const int row = 8*w + 2*p + (lane >> 5);
      const int g   = (lane & 31) ^ (row & 7);
      dma16(kT + (bN + j0 + row) * C_ + g * 8, &Kbuf[buf][(8*w + 2*p) * 256]);
    }
    #pragma unroll
    for (int p = 0; p < 4; ++p) {          // V: 256 rows x 4 granules
      const int row = 64*w + 16*p + (lane >> 2);
      const int g   = (lane & 3) ^ ((row >> 1) & 3);
      dma16(vW + (bC + row) * N_ + j0 + g * 8, &Vbuf[buf][(64*w + 16*p) * 32]);
    }
  };

  stage(0, 0);

  // Q fragments resident: i = i0 + w*16 + m16
  bf16x8 qf[8];
  {
    const unsigned short* qbase = qT + ((bN + i0 + w*16 + m16) * C_ + q8);
    #pragma unroll
    for (int ks = 0; ks < 8; ++ks) qf[ks] = *(const bf16x8*)(qbase + ks*32);
  }

  float l_lane = 0.0f;
  f32x4 Oacc[16] = {};     // O^T: col=i (lane&15), row=c (q*4+reg)

  for (int jt = 0; jt < 128; ++jt) {
    asm volatile("s_waitcnt vmcnt(0)" ::: "memory");
    __syncthreads();
    if (jt + 1 < 128) stage((jt + 1) & 1, (jt + 1) * 32);

    const unsigned short* Kt = Kbuf[jt & 1];
    const unsigned short* Vt = Vbuf[jt & 1];

    // --- S^T = K * Q^T : col=i=lane&15, row j = jb*16 + q*4 + reg ---
    f32x4 st[2] = {};
    #pragma unroll
    for (int ks = 0; ks < 8; ++ks) {
      #pragma unroll
      for (int jb = 0; jb < 2; ++jb) {
        const int j = jb*16 + m16;
        bf16x8 a = *(const bf16x8*)&Kt[j * 256 + (((4*ks + q) ^ (j & 7)) * 8)];
        st[jb] = __builtin_amdgcn_mfma_f32_16x16x32_bf16(a, qf[ks], st[jb], 0,0,0);
      }
    }

    // --- fixed-max softmax: p = exp(S - 64) ---
    float ps[2][4];
    #pragma unroll
    for (int jb = 0; jb < 2; ++jb)
      #pragma unroll
      for (int r = 0; r < 4; ++r) {
        const float p = __expf(st[jb][r] - 64.0f);
        ps[jb][r] = p;
        l_lane += p;
      }
    union { uint4 u; bf16x8 v; } pk;
    pk.u.x = (unsigned)f2bf(ps[0][0]) | ((unsigned)f2bf(ps[0][1]) << 16);
    pk.u.y = (unsigned)f2bf(ps[0][2]) | ((unsigned)f2bf(ps[0][3]) << 16);
    pk.u.z = (unsigned)f2bf(ps[1][0]) | ((unsigned)f2bf(ps[1][1]) << 16);
    pk.u.w = (unsigned)f2bf(ps[1][2]) | ((unsigned)f2bf(ps[1][3]) << 16);

    // --- O^T += V * P^T ; V granule q of permuted row = both needed j-chunks
    #pragma unroll
    for (int cb = 0; cb < 16; ++cb) {
      const int c = cb*16 + m16;
      bf16x8 vf = *(const bf16x8*)&Vt[c * 32 + ((q ^ ((c >> 1) & 3)) * 8)];
      Oacc[cb] = __builtin_amdgcn_mfma_f32_16x16x32_bf16(vf, pk.v, Oacc[cb], 0,0,0);
    }
  }

  // --- reduce l across q-groups ---
  float l = l_lane;
  l += __shfl_xor(l, 16);
  l += __shfl_xor(l, 32);

  // --- epilogue: out[b][c][i] = gamma * O^T[c][i] / (l_i * 64) + x[b][c][i] ---
  const float gm = gamma[0];
  const float fs = gm / (l * 64.0f);
  const int icol = i0 + w*16 + m16;
  #pragma unroll
  for (int cb = 0; cb < 16; ++cb) {
    #pragma unroll
    for (int r = 0; r < 4; ++r) {
      const int c = cb*16 + q*4 + r;
      const size_t idx = (bC + c) * N_ + icol;
      out[idx] = Oacc[cb][r] * fs + x[idx];
    }
  }
}

extern "C" void kernel_launch(void* const* d_in, const int* in_sizes, int n_in,
                              void* d_out, int out_size, void* d_ws, size_t ws_size,
                              hipStream_t stream) {
  const float* x     = (const float*)d_in[0];
  const float* Wq    = (const float*)d_in[1];
  const float* bq    = (const float*)d_in[2];
  const float* Wk    = (const float*)d_in[3];
  const float* bk    = (const float*)d_in[4];
  const float* Wv    = (const float*)d_in[5];
  const float* bv    = (const float*)d_in[6];
  const float* gamma = (const float*)d_in[7];
  float* out = (float*)d_out;

  unsigned short* xT  = (unsigned short*)d_ws;            // 16 MB
  unsigned short* Wbf = xT + (size_t)B_ * N_ * C_;        // 384 KB
  unsigned short* qT  = Wbf + 3 * 65536;                  // 16 MB
  unsigned short* kT  = qT + (size_t)B_ * N_ * C_;        // 16 MB
  unsigned short* vW  = kT + (size_t)B_ * N_ * C_;        // 16 MB

  prep<<<dim3(64, 4, 8), dim3(256), 0, stream>>>(x, Wq, Wk, Wv, xT, Wbf);
  qkv_gemm<<<dim3(64, 8, 3), dim3(256), 0, stream>>>(xT, Wbf, bq, bk, bv, qT, kT, vW);
  attn5<<<dim3(8, 64), dim3(256), 0, stream>>>(qT, kT, vW, x, gamma, out);
}